// Round 1
// baseline (47.897 us; speedup 1.0000x reference)
//
#include <hip/hip_runtime.h>

#define BB 4
#define CC 3
#define HH 1024
#define WW 1024

__global__ __launch_bounds__(256) void dpmerge_kernel(
    const float* __restrict__ image,   // (B,C,H,W)
    const float* __restrict__ depth,   // (B,H,W)
    float* __restrict__ out)           // left (B,C,H,W) then right (B,C,H,W)
{
    __shared__ float sd[WW];
    __shared__ float si[CC][WW];

    const int row = blockIdx.x;        // 0 .. B*H-1
    const int b   = row >> 10;         // / H
    const int h   = row & (HH - 1);    // % H
    const int tid = threadIdx.x;

    // Stage depth row (1024 floats) and 3 image channel rows via float4.
    reinterpret_cast<float4*>(sd)[tid] =
        reinterpret_cast<const float4*>(depth + (size_t)row * WW)[tid];
#pragma unroll
    for (int c = 0; c < CC; ++c) {
        reinterpret_cast<float4*>(si[c])[tid] =
            reinterpret_cast<const float4*>(
                image + (((size_t)b * CC + c) * HH + h) * WW)[tid];
    }
    __syncthreads();

    const size_t chStride = (size_t)HH * WW;
    const size_t outBase  = ((size_t)b * CC * HH + h) * (size_t)WW; // + c*chStride + x
    const size_t NV       = (size_t)BB * CC * HH * WW;              // right-view offset

#pragma unroll
    for (int k = 0; k < 4; ++k) {
        const int x = tid + k * 256;

        float cl = 0.f, cr = 0.f;
        float al0 = 0.f, al1 = 0.f, al2 = 0.f;
        float ar0 = 0.f, ar1 = 0.f, ar2 = 0.f;

        // Left view: pos = s + d, d in [0,8) -> sources s in [x-9, x]
#pragma unroll
        for (int ds = -9; ds <= 0; ++ds) {
            const int s = x + ds;
            if (s < 0) continue;                    // s <= x < W always
            const float d   = sd[s];
            const float pos = (float)s + d;
            const float x0  = floorf(pos);
            const float f   = pos - x0;
            const int   xi  = (int)x0;
            const float wt  = (xi == x) ? (1.f - f)
                            : ((xi + 1 == x) ? f : 0.f);
            cl  += wt;
            al0 = fmaf(si[0][s], wt, al0);
            al1 = fmaf(si[1][s], wt, al1);
            al2 = fmaf(si[2][s], wt, al2);
        }

        // Right view: pos = s - d, d in [0,8) -> sources s in [x-1, x+9]
#pragma unroll
        for (int ds = -1; ds <= 9; ++ds) {
            const int s = x + ds;
            if (s < 0 || s >= WW) continue;
            const float d   = sd[s];
            const float pos = (float)s - d;
            const float x0  = floorf(pos);
            const float f   = pos - x0;
            const int   xi  = (int)x0;
            const float wt  = (xi == x) ? (1.f - f)
                            : ((xi + 1 == x) ? f : 0.f);
            cr  += wt;
            ar0 = fmaf(si[0][s], wt, ar0);
            ar1 = fmaf(si[1][s], wt, ar1);
            ar2 = fmaf(si[2][s], wt, ar2);
        }

        const float denl = (cl == 0.f) ? 1.f : cl;
        const float denr = (cr == 0.f) ? 1.f : cr;

        out[outBase + 0 * chStride + x]      = al0 / denl;
        out[outBase + 1 * chStride + x]      = al1 / denl;
        out[outBase + 2 * chStride + x]      = al2 / denl;
        out[NV + outBase + 0 * chStride + x] = ar0 / denr;
        out[NV + outBase + 1 * chStride + x] = ar1 / denr;
        out[NV + outBase + 2 * chStride + x] = ar2 / denr;
    }
}

extern "C" void kernel_launch(void* const* d_in, const int* in_sizes, int n_in,
                              void* d_out, int out_size, void* d_ws, size_t ws_size,
                              hipStream_t stream) {
    const float* image = (const float*)d_in[0];
    const float* depth = (const float*)d_in[1];
    float* out = (float*)d_out;
    (void)in_sizes; (void)n_in; (void)out_size; (void)d_ws; (void)ws_size;

    dim3 grid(BB * HH);   // 4096 rows
    dim3 block(256);
    hipLaunchKernelGGL(dpmerge_kernel, grid, block, 0, stream, image, depth, out);
}

// Round 2
// 34.295 us; speedup vs baseline: 1.3966x; 1.3966x over previous
//
#include <hip/hip_runtime.h>

#define BB 4
#define CC 3
#define HH 1024
#define WW 1024
#define PAD 8
#define WP (WW + 2 * PAD)   // 1040

__global__ __launch_bounds__(256) void dpmerge_kernel(
    const float* __restrict__ image,   // (B,C,H,W)
    const float* __restrict__ depth,   // (B,H,W)
    float* __restrict__ out)           // left (B,C,H,W) then right (B,C,H,W)
{
    // posL = float(s)+d, posR = float(s)-d (identical fp ops to reference),
    // plus the 3 channel rows. Padded +-8 with poison so no bounds checks.
    __shared__ __align__(16) float pl[WP];
    __shared__ __align__(16) float pr[WP];
    __shared__ __align__(16) float s0[WP];
    __shared__ __align__(16) float s1[WP];
    __shared__ __align__(16) float s2[WP];

    const int row = blockIdx.x;        // 0 .. B*H-1
    const int b   = row >> 10;
    const int h   = row & (HH - 1);
    const int tid = threadIdx.x;

    const size_t chStride = (size_t)HH * WW;
    const size_t imgBase  = ((size_t)b * CC) * chStride + (size_t)h * WW;

    // ---- stage ----
    {
        const float4 dv = reinterpret_cast<const float4*>(depth + (size_t)row * WW)[tid];
        const int   sbi = 4 * tid;
        float4 a, r;
        a.x = (float)(sbi + 0) + dv.x;  r.x = (float)(sbi + 0) - dv.x;
        a.y = (float)(sbi + 1) + dv.y;  r.y = (float)(sbi + 1) - dv.y;
        a.z = (float)(sbi + 2) + dv.z;  r.z = (float)(sbi + 2) - dv.z;
        a.w = (float)(sbi + 3) + dv.w;  r.w = (float)(sbi + 3) - dv.w;
        reinterpret_cast<float4*>(pl + PAD)[tid] = a;
        reinterpret_cast<float4*>(pr + PAD)[tid] = r;

        const float4 v0 = reinterpret_cast<const float4*>(image + imgBase)[tid];
        const float4 v1 = reinterpret_cast<const float4*>(image + imgBase + chStride)[tid];
        const float4 v2 = reinterpret_cast<const float4*>(image + imgBase + 2 * chStride)[tid];
        reinterpret_cast<float4*>(s0 + PAD)[tid] = v0;
        reinterpret_cast<float4*>(s1 + PAD)[tid] = v1;
        reinterpret_cast<float4*>(s2 + PAD)[tid] = v2;
    }
    if (tid < 2 * PAD) {
        const int idx = (tid < PAD) ? tid : (WW + tid);  // 0..7 and 1032..1039
        pl[idx] = 1e30f;
        pr[idx] = 1e30f;
        s0[idx] = 0.f;
        s1[idx] = 0.f;
        s2[idx] = 0.f;
    }
    __syncthreads();

    const size_t NV = (size_t)BB * CC * chStride;   // right-view offset in out

#pragma unroll
    for (int k = 0; k < 4; ++k) {
        const int   x  = tid + k * 256;
        const float xf = (float)x;

        float cl = 0.f, al0 = 0.f, al1 = 0.f, al2 = 0.f;
        float cr = 0.f, ar0 = 0.f, ar1 = 0.f, ar2 = 0.f;

        // Left view: sources s = x+o, o in [-8,0]; wt = max(0, 1-|posL-x|)
#pragma unroll
        for (int o = -PAD; o <= 0; ++o) {
            const int   ix = x + o + PAD;
            const float t  = pl[ix] - xf;
            const float wt = fmaxf(1.0f - fabsf(t), 0.0f);
            cl += wt;
            al0 = fmaf(s0[ix], wt, al0);
            al1 = fmaf(s1[ix], wt, al1);
            al2 = fmaf(s2[ix], wt, al2);
        }
        // Right view: sources s = x+o, o in [0,8]; wt = max(0, 1-|posR-x|)
#pragma unroll
        for (int o = 0; o <= PAD; ++o) {
            const int   ix = x + o + PAD;
            const float t  = pr[ix] - xf;
            const float wt = fmaxf(1.0f - fabsf(t), 0.0f);
            cr += wt;
            ar0 = fmaf(s0[ix], wt, ar0);
            ar1 = fmaf(s1[ix], wt, ar1);
            ar2 = fmaf(s2[ix], wt, ar2);
        }

        const float dl = (cl == 0.f) ? 1.f : cl;
        const float dr = (cr == 0.f) ? 1.f : cr;
        const float il = __builtin_amdgcn_rcpf(dl);
        const float ir = __builtin_amdgcn_rcpf(dr);

        out[imgBase + x]                     = al0 * il;
        out[imgBase + chStride + x]          = al1 * il;
        out[imgBase + 2 * chStride + x]      = al2 * il;
        out[NV + imgBase + x]                = ar0 * ir;
        out[NV + imgBase + chStride + x]     = ar1 * ir;
        out[NV + imgBase + 2 * chStride + x] = ar2 * ir;
    }
}

extern "C" void kernel_launch(void* const* d_in, const int* in_sizes, int n_in,
                              void* d_out, int out_size, void* d_ws, size_t ws_size,
                              hipStream_t stream) {
    const float* image = (const float*)d_in[0];
    const float* depth = (const float*)d_in[1];
    float* out = (float*)d_out;
    (void)in_sizes; (void)n_in; (void)out_size; (void)d_ws; (void)ws_size;

    dim3 grid(BB * HH);   // 4096 rows
    dim3 block(256);
    hipLaunchKernelGGL(dpmerge_kernel, grid, block, 0, stream, image, depth, out);
}

// Round 3
// 32.454 us; speedup vs baseline: 1.4758x; 1.0567x over previous
//
#include <hip/hip_runtime.h>

#define BB 4
#define CC 3
#define HH 1024
#define WW 1024
#define PAD 8
#define WP (WW + 2 * PAD)   // 1040 floats, float4-aligned (260 chunks)

__global__ __launch_bounds__(256) void dpmerge_kernel(
    const float* __restrict__ image,   // (B,C,H,W)
    const float* __restrict__ depth,   // (B,H,W)
    float* __restrict__ out)           // left (B,C,H,W) then right (B,C,H,W)
{
    __shared__ __align__(16) float pl[WP];
    __shared__ __align__(16) float pr[WP];
    __shared__ __align__(16) float s0[WP];
    __shared__ __align__(16) float s1[WP];
    __shared__ __align__(16) float s2[WP];

    const int row = blockIdx.x;        // 0 .. B*H-1
    const int b   = row >> 10;
    const int h   = row & (HH - 1);
    const int tid = threadIdx.x;

    const size_t chStride = (size_t)HH * WW;
    const size_t imgBase  = ((size_t)b * CC) * chStride + (size_t)h * WW;

    // ---- stage: pos arrays (s +- d, same fp op as reference) + 3 channels ----
    {
        const float4 dv = reinterpret_cast<const float4*>(depth + (size_t)row * WW)[tid];
        const int   sbi = 4 * tid;
        float4 a, r;
        a.x = (float)(sbi + 0) + dv.x;  r.x = (float)(sbi + 0) - dv.x;
        a.y = (float)(sbi + 1) + dv.y;  r.y = (float)(sbi + 1) - dv.y;
        a.z = (float)(sbi + 2) + dv.z;  r.z = (float)(sbi + 2) - dv.z;
        a.w = (float)(sbi + 3) + dv.w;  r.w = (float)(sbi + 3) - dv.w;
        reinterpret_cast<float4*>(pl + PAD)[tid] = a;
        reinterpret_cast<float4*>(pr + PAD)[tid] = r;

        const float4 v0 = reinterpret_cast<const float4*>(image + imgBase)[tid];
        const float4 v1 = reinterpret_cast<const float4*>(image + imgBase + chStride)[tid];
        const float4 v2 = reinterpret_cast<const float4*>(image + imgBase + 2 * chStride)[tid];
        reinterpret_cast<float4*>(s0 + PAD)[tid] = v0;
        reinterpret_cast<float4*>(s1 + PAD)[tid] = v1;
        reinterpret_cast<float4*>(s2 + PAD)[tid] = v2;
    }
    if (tid < 2 * PAD) {
        const int idx = (tid < PAD) ? tid : (WW + tid);  // 0..7 and 1032..1039
        pl[idx] = 1e30f;    // poison -> weight 0 naturally
        pr[idx] = 1e30f;
        s0[idx] = 0.f;
        s1[idx] = 0.f;
        s2[idx] = 0.f;
    }
    __syncthreads();

    const size_t NV = (size_t)BB * CC * chStride;   // right-view offset in out
    const int    x0 = 4 * tid;

    const float4* PL = reinterpret_cast<const float4*>(pl);
    const float4* PR = reinterpret_cast<const float4*>(pr);
    const float4* S0 = reinterpret_cast<const float4*>(s0);
    const float4* S1 = reinterpret_cast<const float4*>(s1);
    const float4* S2 = reinterpret_cast<const float4*>(s2);

#define LOAD12(dst, SRC, c0)                                  \
    {                                                         \
        const float4 _a = (SRC)[(c0)];                        \
        const float4 _b = (SRC)[(c0) + 1];                    \
        const float4 _c = (SRC)[(c0) + 2];                    \
        dst[0] = _a.x; dst[1]  = _a.y; dst[2]  = _a.z; dst[3]  = _a.w; \
        dst[4] = _b.x; dst[5]  = _b.y; dst[6]  = _b.z; dst[7]  = _b.w; \
        dst[8] = _c.x; dst[9]  = _c.y; dst[10] = _c.z; dst[11] = _c.w; \
    }

    // ================= LEFT view: sources s in [x0-8, x0+3] =================
    {
        float pw[12], i0[12], i1[12], i2[12];
        LOAD12(pw, PL, tid);        // padded idx 4*tid .. +11  == s in [x0-8, x0+3]
        LOAD12(i0, S0, tid);
        LOAD12(i1, S1, tid);
        LOAD12(i2, S2, tid);

        float4 oc0, oc1, oc2;
        float* o0 = &oc0.x; float* o1 = &oc1.x; float* o2 = &oc2.x;
#pragma unroll
        for (int j = 0; j < 4; ++j) {
            const float xf = (float)(x0 + j);
            float cl = 0.f, a0 = 0.f, a1 = 0.f, a2 = 0.f;
#pragma unroll
            for (int i = 0; i < 9; ++i) {
                const float t  = pw[j + i] - xf;
                const float wt = fmaxf(1.0f - fabsf(t), 0.0f);
                cl += wt;
                a0 = fmaf(i0[j + i], wt, a0);
                a1 = fmaf(i1[j + i], wt, a1);
                a2 = fmaf(i2[j + i], wt, a2);
            }
            const float inv = __builtin_amdgcn_rcpf((cl == 0.f) ? 1.f : cl);
            o0[j] = a0 * inv;
            o1[j] = a1 * inv;
            o2[j] = a2 * inv;
        }
        *reinterpret_cast<float4*>(out + imgBase + x0)                = oc0;
        *reinterpret_cast<float4*>(out + imgBase + chStride + x0)     = oc1;
        *reinterpret_cast<float4*>(out + imgBase + 2 * chStride + x0) = oc2;
    }

    // ================= RIGHT view: sources s in [x0, x0+11] =================
    {
        float pw[12], i0[12], i1[12], i2[12];
        LOAD12(pw, PR, tid + 2);    // padded idx 4*tid+8 .. +19 == s in [x0, x0+11]
        LOAD12(i0, S0, tid + 2);
        LOAD12(i1, S1, tid + 2);
        LOAD12(i2, S2, tid + 2);

        float4 oc0, oc1, oc2;
        float* o0 = &oc0.x; float* o1 = &oc1.x; float* o2 = &oc2.x;
#pragma unroll
        for (int j = 0; j < 4; ++j) {
            const float xf = (float)(x0 + j);
            float cr = 0.f, a0 = 0.f, a1 = 0.f, a2 = 0.f;
#pragma unroll
            for (int i = 0; i < 9; ++i) {
                const float t  = pw[j + i] - xf;
                const float wt = fmaxf(1.0f - fabsf(t), 0.0f);
                cr += wt;
                a0 = fmaf(i0[j + i], wt, a0);
                a1 = fmaf(i1[j + i], wt, a1);
                a2 = fmaf(i2[j + i], wt, a2);
            }
            const float inv = __builtin_amdgcn_rcpf((cr == 0.f) ? 1.f : cr);
            o0[j] = a0 * inv;
            o1[j] = a1 * inv;
            o2[j] = a2 * inv;
        }
        *reinterpret_cast<float4*>(out + NV + imgBase + x0)                = oc0;
        *reinterpret_cast<float4*>(out + NV + imgBase + chStride + x0)     = oc1;
        *reinterpret_cast<float4*>(out + NV + imgBase + 2 * chStride + x0) = oc2;
    }
#undef LOAD12
}

extern "C" void kernel_launch(void* const* d_in, const int* in_sizes, int n_in,
                              void* d_out, int out_size, void* d_ws, size_t ws_size,
                              hipStream_t stream) {
    const float* image = (const float*)d_in[0];
    const float* depth = (const float*)d_in[1];
    float* out = (float*)d_out;
    (void)in_sizes; (void)n_in; (void)out_size; (void)d_ws; (void)ws_size;

    dim3 grid(BB * HH);   // 4096 rows
    dim3 block(256);
    hipLaunchKernelGGL(dpmerge_kernel, grid, block, 0, stream, image, depth, out);
}